// Round 2
// baseline (855.167 us; speedup 1.0000x reference)
//
#include <hip/hip_runtime.h>
#include <hip/hip_bf16.h>

// Flash-attention forward, B=4 H=16 S=2048 D=128, fp32 in/out, no 1/sqrt(D) scale.
// Round 1: precision fix — split-bf16 (hi/lo) QK^T: S = Qh*Kh + Ql*Kh + Qh*Kl.
//   grid = (S/QBLK, B*H), block = 256 (4 waves), wave owns 16 q-rows.

#define QBLK   64
#define KVBLK  64
#define DHEAD  128
#define SEQ    2048
#define KPAD   136   // 128+8 bf16 -> row stride 272 B (16B-aligned, 2-way max conflict)
#define VPAD   72    // 64+8
#define PPAD   72    // 64+8

typedef __bf16 bf16x8 __attribute__((ext_vector_type(8)));
typedef float  f32x4  __attribute__((ext_vector_type(4)));

__global__ __launch_bounds__(256, 2)
void attn_fwd_kernel(const float* __restrict__ Q, const float* __restrict__ K,
                     const float* __restrict__ V, float* __restrict__ O) {
    __shared__ __align__(16) __bf16 Kh_lds[KVBLK * KPAD];
    __shared__ __align__(16) __bf16 Kl_lds[KVBLK * KPAD];
    __shared__ __align__(16) __bf16 Vt_lds[DHEAD * VPAD];
    __shared__ __align__(16) __bf16 P_lds[4 * 16 * PPAD];

    const int tid  = threadIdx.x;
    const int lane = tid & 63;
    const int wave = tid >> 6;
    const int g    = lane >> 4;   // lane-group 0..3
    const int lg   = lane & 15;

    const int qtile = blockIdx.x;
    const int bh    = blockIdx.y;
    const size_t base = (size_t)bh * SEQ * DHEAD;
    const float* Qg = Q + base + (size_t)(qtile * QBLK) * DHEAD;
    const float* Kg = K + base;
    const float* Vg = V + base;
    float*       Og = O + base + (size_t)(qtile * QBLK) * DHEAD;

    // ---- Q fragments in registers, hi/lo split. A-layout: row=lane&15, k=(lane>>4)*8+i
    bf16x8 qh[4], ql[4];
    {
        const float* qrow = Qg + (size_t)(wave * 16 + lg) * DHEAD;
        #pragma unroll
        for (int dc = 0; dc < 4; ++dc) {
            const int d0 = dc * 32 + g * 8;
            float4 f0 = *(const float4*)(qrow + d0);
            float4 f1 = *(const float4*)(qrow + d0 + 4);
            float f[8] = {f0.x, f0.y, f0.z, f0.w, f1.x, f1.y, f1.z, f1.w};
            #pragma unroll
            for (int i = 0; i < 8; ++i) {
                __bf16 h = (__bf16)f[i];
                qh[dc][i] = h;
                ql[dc][i] = (__bf16)(f[i] - (float)h);
            }
        }
    }

    // ---- online-softmax state + output accumulators
    f32x4 acc[8];
    #pragma unroll
    for (int dt = 0; dt < 8; ++dt) { acc[dt][0]=0.f; acc[dt][1]=0.f; acc[dt][2]=0.f; acc[dt][3]=0.f; }
    float m[4], l[4];
    #pragma unroll
    for (int r = 0; r < 4; ++r) { m[r] = -1e30f; l[r] = 0.f; }

    for (int t = 0; t < SEQ / KVBLK; ++t) {
        // ---- stage K tile (row-major bf16 hi/lo, padded)
        {
            const float* Kt = Kg + (size_t)t * KVBLK * DHEAD;
            #pragma unroll
            for (int j = 0; j < 4; ++j) {
                const int c   = tid + 256 * j;      // 0..1023
                const int row = c >> 4;
                const int dc  = (c & 15) * 8;
                float4 f0 = *(const float4*)(Kt + row * DHEAD + dc);
                float4 f1 = *(const float4*)(Kt + row * DHEAD + dc + 4);
                float f[8] = {f0.x, f0.y, f0.z, f0.w, f1.x, f1.y, f1.z, f1.w};
                bf16x8 vh, vl;
                #pragma unroll
                for (int i = 0; i < 8; ++i) {
                    __bf16 h = (__bf16)f[i];
                    vh[i] = h;
                    vl[i] = (__bf16)(f[i] - (float)h);
                }
                *(bf16x8*)&Kh_lds[row * KPAD + dc] = vh;
                *(bf16x8*)&Kl_lds[row * KPAD + dc] = vl;
            }
            // ---- stage V tile transposed: Vt_lds[d][kv]
            const float* Vt = Vg + (size_t)t * KVBLK * DHEAD;
            #pragma unroll
            for (int j = 0; j < 8; ++j) {
                const int c   = tid + 256 * j;      // 0..2047
                const int row = c >> 5;             // kv row 0..63
                const int d0  = (c & 31) * 4;
                float4 f = *(const float4*)(Vt + row * DHEAD + d0);
                Vt_lds[(d0 + 0) * VPAD + row] = (__bf16)f.x;
                Vt_lds[(d0 + 1) * VPAD + row] = (__bf16)f.y;
                Vt_lds[(d0 + 2) * VPAD + row] = (__bf16)f.z;
                Vt_lds[(d0 + 3) * VPAD + row] = (__bf16)f.w;
            }
        }
        __syncthreads();

        // ---- S = Q * K^T with hi/lo compensation (16 q-rows x 64 kv-cols per wave)
        f32x4 s[4];
        #pragma unroll
        for (int ct = 0; ct < 4; ++ct) {
            f32x4 a; a[0]=0.f; a[1]=0.f; a[2]=0.f; a[3]=0.f;
            #pragma unroll
            for (int dc = 0; dc < 4; ++dc) {
                const int off = (ct * 16 + lg) * KPAD + dc * 32 + g * 8;
                bf16x8 kh = *(const bf16x8*)&Kh_lds[off];
                bf16x8 kl = *(const bf16x8*)&Kl_lds[off];
                a = __builtin_amdgcn_mfma_f32_16x16x32_bf16(qh[dc], kh, a, 0, 0, 0);
                a = __builtin_amdgcn_mfma_f32_16x16x32_bf16(ql[dc], kh, a, 0, 0, 0);
                a = __builtin_amdgcn_mfma_f32_16x16x32_bf16(qh[dc], kl, a, 0, 0, 0);
            }
            s[ct] = a;
        }

        // ---- online softmax (per q-row r; row lives in 16-lane group)
        #pragma unroll
        for (int r = 0; r < 4; ++r) {
            float rowmax = fmaxf(fmaxf(s[0][r], s[1][r]), fmaxf(s[2][r], s[3][r]));
            #pragma unroll
            for (int off = 1; off < 16; off <<= 1)
                rowmax = fmaxf(rowmax, __shfl_xor(rowmax, off));
            const float mnew = fmaxf(m[r], rowmax);
            const float sc   = __expf(m[r] - mnew);
            m[r] = mnew;
            float rs = 0.f;
            #pragma unroll
            for (int ct = 0; ct < 4; ++ct) {
                float p = __expf(s[ct][r] - mnew);
                s[ct][r] = p;
                rs += p;
            }
            #pragma unroll
            for (int off = 1; off < 16; off <<= 1)
                rs += __shfl_xor(rs, off);
            l[r] = l[r] * sc + rs;
            #pragma unroll
            for (int dt = 0; dt < 8; ++dt) acc[dt][r] *= sc;
        }

        // ---- P (C/D layout) -> LDS -> A-fragment layout
        __bf16* pbase = &P_lds[wave * 16 * PPAD];
        #pragma unroll
        for (int ct = 0; ct < 4; ++ct)
            #pragma unroll
            for (int r = 0; r < 4; ++r)
                pbase[(g * 4 + r) * PPAD + ct * 16 + lg] = (__bf16)s[ct][r];

        // ---- O += P * V
        #pragma unroll
        for (int kt = 0; kt < 2; ++kt) {
            bf16x8 pf = *(const bf16x8*)&pbase[lg * PPAD + kt * 32 + g * 8];
            #pragma unroll
            for (int dt = 0; dt < 8; ++dt) {
                bf16x8 vf = *(const bf16x8*)&Vt_lds[(dt * 16 + lg) * VPAD + kt * 32 + g * 8];
                acc[dt] = __builtin_amdgcn_mfma_f32_16x16x32_bf16(pf, vf, acc[dt], 0, 0, 0);
            }
        }
        __syncthreads();
    }

    // ---- epilogue: O / l
    float inv[4];
    #pragma unroll
    for (int r = 0; r < 4; ++r) inv[r] = 1.f / l[r];
    float* ob = Og + (size_t)(wave * 16) * DHEAD;
    #pragma unroll
    for (int dt = 0; dt < 8; ++dt)
        #pragma unroll
        for (int r = 0; r < 4; ++r)
            ob[(size_t)(g * 4 + r) * DHEAD + dt * 16 + lg] = acc[dt][r] * inv[r];
}

extern "C" void kernel_launch(void* const* d_in, const int* in_sizes, int n_in,
                              void* d_out, int out_size, void* d_ws, size_t ws_size,
                              hipStream_t stream) {
    const float* q = (const float*)d_in[0];
    const float* k = (const float*)d_in[1];
    const float* v = (const float*)d_in[2];
    float* out = (float*)d_out;
    const int BH = in_sizes[0] / (SEQ * DHEAD);   // 64
    dim3 grid(SEQ / QBLK, BH);
    attn_fwd_kernel<<<grid, dim3(256), 0, stream>>>(q, k, v, out);
}

// Round 4
// 478.713 us; speedup vs baseline: 1.7864x; 1.7864x over previous
//
#include <hip/hip_runtime.h>
#include <hip/hip_bf16.h>

// Flash-attention forward, B=4 H=16 S=2048 D=128, fp32 in/out, no 1/sqrt(D) scale.
// Round 3: fix tr_read per-lane address granularity (lg*8, not lg*2).
//   - V staged in subtiled [kv/4][d/16][4][16] bf16 layout, conflict-free b128 writes,
//     consumed via ds_read_b64_tr_b16 (window = addr&~127, column = (addr&127)>>3).
//   - P_lds XOR-swizzled (col ^ ((row>>2)<<3)) on write+read.
//   - K hi/lo path unchanged (<=2-way, free).

#define QBLK   64
#define KVBLK  64
#define DHEAD  128
#define SEQ    2048
#define KPAD   136   // 128+8 bf16 -> row stride 272 B
#define PPAD   72    // 64+8

typedef __bf16 bf16x8 __attribute__((ext_vector_type(8)));
typedef __bf16 bf16x4 __attribute__((ext_vector_type(4)));
typedef float  f32x4  __attribute__((ext_vector_type(4)));

__global__ __launch_bounds__(256, 2)
void attn_fwd_kernel(const float* __restrict__ Q, const float* __restrict__ K,
                     const float* __restrict__ V, float* __restrict__ O) {
    __shared__ __align__(16) __bf16 Kh_lds[KVBLK * KPAD];
    __shared__ __align__(16) __bf16 Kl_lds[KVBLK * KPAD];
    __shared__ __align__(16) __bf16 V_lds[KVBLK * DHEAD];   // subtiled [kv/4][d/16][4][16]
    __shared__ __align__(16) __bf16 P_lds[4 * 16 * PPAD];

    const int tid  = threadIdx.x;
    const int lane = tid & 63;
    const int wave = tid >> 6;
    const int g    = lane >> 4;   // lane-group 0..3
    const int lg   = lane & 15;

    const int qtile = blockIdx.x;
    const int bh    = blockIdx.y;
    const size_t base = (size_t)bh * SEQ * DHEAD;
    const float* Qg = Q + base + (size_t)(qtile * QBLK) * DHEAD;
    const float* Kg = K + base;
    const float* Vg = V + base;
    float*       Og = O + base + (size_t)(qtile * QBLK) * DHEAD;

    // per-lane base byte-address for ds_read_b64_tr_b16 on V_lds:
    //   window (128B subtile) = kt*8192 + g*2048 + s*1024 + dt*128  (kt,s,dt via offset:)
    //   column within window  = lg  -> lane-offset lg*8 bytes
    const unsigned trbase = (unsigned)(size_t)&V_lds[0] + (unsigned)(g * 2048 + lg * 8);

    // ---- Q fragments in registers, hi/lo split. A-layout: row=lane&15, k=(lane>>4)*8+i
    bf16x8 qh[4], ql[4];
    {
        const float* qrow = Qg + (size_t)(wave * 16 + lg) * DHEAD;
        #pragma unroll
        for (int dc = 0; dc < 4; ++dc) {
            const int d0 = dc * 32 + g * 8;
            float4 f0 = *(const float4*)(qrow + d0);
            float4 f1 = *(const float4*)(qrow + d0 + 4);
            float f[8] = {f0.x, f0.y, f0.z, f0.w, f1.x, f1.y, f1.z, f1.w};
            #pragma unroll
            for (int i = 0; i < 8; ++i) {
                __bf16 h = (__bf16)f[i];
                qh[dc][i] = h;
                ql[dc][i] = (__bf16)(f[i] - (float)h);
            }
        }
    }

    // ---- online-softmax state + output accumulators
    f32x4 acc[8];
    #pragma unroll
    for (int dt = 0; dt < 8; ++dt) { acc[dt][0]=0.f; acc[dt][1]=0.f; acc[dt][2]=0.f; acc[dt][3]=0.f; }
    float m[4], l[4];
    #pragma unroll
    for (int r = 0; r < 4; ++r) { m[r] = -1e30f; l[r] = 0.f; }

    for (int t = 0; t < SEQ / KVBLK; ++t) {
        // ---- stage K tile (row-major bf16 hi/lo, padded; <=2-way banks)
        {
            const float* Kt = Kg + (size_t)t * KVBLK * DHEAD;
            #pragma unroll
            for (int j = 0; j < 4; ++j) {
                const int c   = tid + 256 * j;      // 0..1023
                const int row = c >> 4;
                const int dc  = (c & 15) * 8;
                float4 f0 = *(const float4*)(Kt + row * DHEAD + dc);
                float4 f1 = *(const float4*)(Kt + row * DHEAD + dc + 4);
                float f[8] = {f0.x, f0.y, f0.z, f0.w, f1.x, f1.y, f1.z, f1.w};
                bf16x8 vh, vl;
                #pragma unroll
                for (int i = 0; i < 8; ++i) {
                    __bf16 h = (__bf16)f[i];
                    vh[i] = h;
                    vl[i] = (__bf16)(f[i] - (float)h);
                }
                *(bf16x8*)&Kh_lds[row * KPAD + dc] = vh;
                *(bf16x8*)&Kl_lds[row * KPAD + dc] = vl;
            }
            // ---- stage V tile into subtiled layout [kv/4][d/16][4][16]
            //      lane->(row,d8) remap for conflict-free b128 writes:
            //      bank_start = 8*(row&3) + 4*(d8&1) sweeps 0,4,...,28 per 8 lanes.
            const float* Vt = Vg + (size_t)t * KVBLK * DHEAD;
            #pragma unroll
            for (int j = 0; j < 4; ++j) {
                const int c   = tid + 256 * j;                 // 0..1023
                const int d8  = (c & 1) | (((c >> 3) & 7) << 1);   // 0..15
                const int row = ((c >> 1) & 3) | ((c >> 6) << 2);  // 0..63
                const int d0  = d8 * 8;
                float4 f0 = *(const float4*)(Vt + row * DHEAD + d0);
                float4 f1 = *(const float4*)(Vt + row * DHEAD + d0 + 4);
                bf16x8 vv;
                vv[0]=(__bf16)f0.x; vv[1]=(__bf16)f0.y; vv[2]=(__bf16)f0.z; vv[3]=(__bf16)f0.w;
                vv[4]=(__bf16)f1.x; vv[5]=(__bf16)f1.y; vv[6]=(__bf16)f1.z; vv[7]=(__bf16)f1.w;
                const int st = (row >> 2) * 8 + (d0 >> 4);
                *(bf16x8*)&V_lds[st * 64 + (row & 3) * 16 + (d0 & 15)] = vv;
            }
        }
        __syncthreads();

        // ---- S = Q * K^T with hi/lo compensation (16 q-rows x 64 kv-cols per wave)
        f32x4 s[4];
        #pragma unroll
        for (int ct = 0; ct < 4; ++ct) {
            f32x4 a; a[0]=0.f; a[1]=0.f; a[2]=0.f; a[3]=0.f;
            #pragma unroll
            for (int dc = 0; dc < 4; ++dc) {
                const int off = (ct * 16 + lg) * KPAD + dc * 32 + g * 8;
                bf16x8 kh = *(const bf16x8*)&Kh_lds[off];
                bf16x8 kl = *(const bf16x8*)&Kl_lds[off];
                a = __builtin_amdgcn_mfma_f32_16x16x32_bf16(qh[dc], kh, a, 0, 0, 0);
                a = __builtin_amdgcn_mfma_f32_16x16x32_bf16(ql[dc], kh, a, 0, 0, 0);
                a = __builtin_amdgcn_mfma_f32_16x16x32_bf16(qh[dc], kl, a, 0, 0, 0);
            }
            s[ct] = a;
        }

        // ---- online softmax (per q-row r; row lives in 16-lane group)
        #pragma unroll
        for (int r = 0; r < 4; ++r) {
            float rowmax = fmaxf(fmaxf(s[0][r], s[1][r]), fmaxf(s[2][r], s[3][r]));
            #pragma unroll
            for (int off = 1; off < 16; off <<= 1)
                rowmax = fmaxf(rowmax, __shfl_xor(rowmax, off));
            const float mnew = fmaxf(m[r], rowmax);
            const float sc   = __expf(m[r] - mnew);
            m[r] = mnew;
            float rs = 0.f;
            #pragma unroll
            for (int ct = 0; ct < 4; ++ct) {
                float p = __expf(s[ct][r] - mnew);
                s[ct][r] = p;
                rs += p;
            }
            #pragma unroll
            for (int off = 1; off < 16; off <<= 1)
                rs += __shfl_xor(rs, off);
            l[r] = l[r] * sc + rs;
            #pragma unroll
            for (int dt = 0; dt < 8; ++dt) acc[dt][r] *= sc;
        }

        // ---- P (C/D layout) -> LDS (XOR-swizzled) -> A-fragment layout
        __bf16* pbase = &P_lds[wave * 16 * PPAD];
        #pragma unroll
        for (int ct = 0; ct < 4; ++ct)
            #pragma unroll
            for (int r = 0; r < 4; ++r)
                pbase[(g * 4 + r) * PPAD + ((ct * 16 + lg) ^ (g << 3))] = (__bf16)s[ct][r];

        // ---- O += P * V  (V via ds_read_b64_tr_b16 from subtiled layout)
        #pragma unroll
        for (int kt = 0; kt < 2; ++kt) {
            bf16x8 pf = *(const bf16x8*)&pbase[lg * PPAD + ((kt * 32 + g * 8) ^ ((lg >> 2) << 3))];
            #pragma unroll
            for (int dp = 0; dp < 4; ++dp) {
                bf16x4 a0, a1, b0, b1;
                asm volatile(
                    "ds_read_b64_tr_b16 %0, %4 offset:%5\n\t"
                    "ds_read_b64_tr_b16 %1, %4 offset:%6\n\t"
                    "ds_read_b64_tr_b16 %2, %4 offset:%7\n\t"
                    "ds_read_b64_tr_b16 %3, %4 offset:%8\n\t"
                    "s_waitcnt lgkmcnt(0)"
                    : "=&v"(a0), "=&v"(a1), "=&v"(b0), "=&v"(b1)
                    : "v"(trbase),
                      "i"(kt * 8192 + (dp * 2 + 0) * 128),
                      "i"(kt * 8192 + 1024 + (dp * 2 + 0) * 128),
                      "i"(kt * 8192 + (dp * 2 + 1) * 128),
                      "i"(kt * 8192 + 1024 + (dp * 2 + 1) * 128)
                    : "memory");
                __builtin_amdgcn_sched_barrier(0);
                bf16x8 vf0 = __builtin_shufflevector(a0, a1, 0, 1, 2, 3, 4, 5, 6, 7);
                bf16x8 vf1 = __builtin_shufflevector(b0, b1, 0, 1, 2, 3, 4, 5, 6, 7);
                acc[dp * 2 + 0] = __builtin_amdgcn_mfma_f32_16x16x32_bf16(pf, vf0, acc[dp * 2 + 0], 0, 0, 0);
                acc[dp * 2 + 1] = __builtin_amdgcn_mfma_f32_16x16x32_bf16(pf, vf1, acc[dp * 2 + 1], 0, 0, 0);
            }
        }
        __syncthreads();
    }

    // ---- epilogue: O / l
    float inv[4];
    #pragma unroll
    for (int r = 0; r < 4; ++r) inv[r] = 1.f / l[r];
    float* ob = Og + (size_t)(wave * 16) * DHEAD;
    #pragma unroll
    for (int dt = 0; dt < 8; ++dt)
        #pragma unroll
        for (int r = 0; r < 4; ++r)
            ob[(size_t)(g * 4 + r) * DHEAD + dt * 16 + lg] = acc[dt][r] * inv[r];
}

extern "C" void kernel_launch(void* const* d_in, const int* in_sizes, int n_in,
                              void* d_out, int out_size, void* d_ws, size_t ws_size,
                              hipStream_t stream) {
    const float* q = (const float*)d_in[0];
    const float* k = (const float*)d_in[1];
    const float* v = (const float*)d_in[2];
    float* out = (float*)d_out;
    const int BH = in_sizes[0] / (SEQ * DHEAD);   // 64
    dim3 grid(SEQ / QBLK, BH);
    attn_fwd_kernel<<<grid, dim3(256), 0, stream>>>(q, k, v, out);
}

// Round 5
// 354.709 us; speedup vs baseline: 2.4109x; 1.3496x over previous
//
#include <hip/hip_runtime.h>
#include <hip/hip_bf16.h>

// Flash-attention forward, B=4 H=16 S=2048 D=128, fp32 in/out, no 1/sqrt(D) scale.
// Round 4: replace bf16 hi/lo with single-precision fp16 (11-bit mantissa, 8x less
//   rounding than bf16 -> predicted QK^T error ~0.023 < 0.1056 threshold).
//   MFMA/tile 64->32, K staging halved, LDS 60->43KB -> 3 blocks/CU.
//   Structure otherwise identical to round 3 (tr_read V, swizzled P).

#define QBLK   64
#define KVBLK  64
#define DHEAD  128
#define SEQ    2048
#define KPAD   136   // 128+8 f16 -> row stride 272 B
#define PPAD   72    // 64+8

typedef _Float16 f16x8 __attribute__((ext_vector_type(8)));
typedef _Float16 f16x4 __attribute__((ext_vector_type(4)));
typedef float    f32x4 __attribute__((ext_vector_type(4)));

__global__ __launch_bounds__(256, 3)
void attn_fwd_kernel(const float* __restrict__ Q, const float* __restrict__ K,
                     const float* __restrict__ V, float* __restrict__ O) {
    __shared__ __align__(16) _Float16 K_lds[KVBLK * KPAD];
    __shared__ __align__(16) _Float16 V_lds[KVBLK * DHEAD];   // subtiled [kv/4][d/16][4][16]
    __shared__ __align__(16) _Float16 P_lds[4 * 16 * PPAD];

    const int tid  = threadIdx.x;
    const int lane = tid & 63;
    const int wave = tid >> 6;
    const int g    = lane >> 4;   // lane-group 0..3
    const int lg   = lane & 15;

    const int qtile = blockIdx.x;
    const int bh    = blockIdx.y;
    const size_t base = (size_t)bh * SEQ * DHEAD;
    const float* Qg = Q + base + (size_t)(qtile * QBLK) * DHEAD;
    const float* Kg = K + base;
    const float* Vg = V + base;
    float*       Og = O + base + (size_t)(qtile * QBLK) * DHEAD;

    // per-lane base byte-address for ds_read_b64_tr_b16 on V_lds:
    //   window (128B subtile) = kt*8192 + g*2048 + s*1024 + dt*128  (kt,s,dt via offset:)
    //   column within window  = lg  -> lane-offset lg*8 bytes
    const unsigned trbase = (unsigned)(size_t)&V_lds[0] + (unsigned)(g * 2048 + lg * 8);

    // ---- Q fragments in registers (fp16). A-layout: row=lane&15, k=(lane>>4)*8+i
    f16x8 qf[4];
    {
        const float* qrow = Qg + (size_t)(wave * 16 + lg) * DHEAD;
        #pragma unroll
        for (int dc = 0; dc < 4; ++dc) {
            const int d0 = dc * 32 + g * 8;
            float4 f0 = *(const float4*)(qrow + d0);
            float4 f1 = *(const float4*)(qrow + d0 + 4);
            qf[dc][0] = (_Float16)f0.x; qf[dc][1] = (_Float16)f0.y;
            qf[dc][2] = (_Float16)f0.z; qf[dc][3] = (_Float16)f0.w;
            qf[dc][4] = (_Float16)f1.x; qf[dc][5] = (_Float16)f1.y;
            qf[dc][6] = (_Float16)f1.z; qf[dc][7] = (_Float16)f1.w;
        }
    }

    // ---- online-softmax state + output accumulators
    f32x4 acc[8];
    #pragma unroll
    for (int dt = 0; dt < 8; ++dt) { acc[dt][0]=0.f; acc[dt][1]=0.f; acc[dt][2]=0.f; acc[dt][3]=0.f; }
    float m[4], l[4];
    #pragma unroll
    for (int r = 0; r < 4; ++r) { m[r] = -1e30f; l[r] = 0.f; }

    for (int t = 0; t < SEQ / KVBLK; ++t) {
        // ---- stage K tile (row-major fp16, padded; <=2-way banks)
        {
            const float* Kt = Kg + (size_t)t * KVBLK * DHEAD;
            #pragma unroll
            for (int j = 0; j < 4; ++j) {
                const int c   = tid + 256 * j;      // 0..1023
                const int row = c >> 4;
                const int dc  = (c & 15) * 8;
                float4 f0 = *(const float4*)(Kt + row * DHEAD + dc);
                float4 f1 = *(const float4*)(Kt + row * DHEAD + dc + 4);
                f16x8 vh;
                vh[0]=(_Float16)f0.x; vh[1]=(_Float16)f0.y; vh[2]=(_Float16)f0.z; vh[3]=(_Float16)f0.w;
                vh[4]=(_Float16)f1.x; vh[5]=(_Float16)f1.y; vh[6]=(_Float16)f1.z; vh[7]=(_Float16)f1.w;
                *(f16x8*)&K_lds[row * KPAD + dc] = vh;
            }
            // ---- stage V tile into subtiled layout [kv/4][d/16][4][16]
            //      lane->(row,d8) remap for conflict-free b128 writes.
            const float* Vt = Vg + (size_t)t * KVBLK * DHEAD;
            #pragma unroll
            for (int j = 0; j < 4; ++j) {
                const int c   = tid + 256 * j;                 // 0..1023
                const int d8  = (c & 1) | (((c >> 3) & 7) << 1);   // 0..15
                const int row = ((c >> 1) & 3) | ((c >> 6) << 2);  // 0..63
                const int d0  = d8 * 8;
                float4 f0 = *(const float4*)(Vt + row * DHEAD + d0);
                float4 f1 = *(const float4*)(Vt + row * DHEAD + d0 + 4);
                f16x8 vv;
                vv[0]=(_Float16)f0.x; vv[1]=(_Float16)f0.y; vv[2]=(_Float16)f0.z; vv[3]=(_Float16)f0.w;
                vv[4]=(_Float16)f1.x; vv[5]=(_Float16)f1.y; vv[6]=(_Float16)f1.z; vv[7]=(_Float16)f1.w;
                const int st = (row >> 2) * 8 + (d0 >> 4);
                *(f16x8*)&V_lds[st * 64 + (row & 3) * 16 + (d0 & 15)] = vv;
            }
        }
        __syncthreads();

        // ---- S = Q * K^T (16 q-rows x 64 kv-cols per wave)
        f32x4 s[4];
        #pragma unroll
        for (int ct = 0; ct < 4; ++ct) {
            f32x4 a; a[0]=0.f; a[1]=0.f; a[2]=0.f; a[3]=0.f;
            #pragma unroll
            for (int dc = 0; dc < 4; ++dc) {
                const int off = (ct * 16 + lg) * KPAD + dc * 32 + g * 8;
                f16x8 kh = *(const f16x8*)&K_lds[off];
                a = __builtin_amdgcn_mfma_f32_16x16x32_f16(qf[dc], kh, a, 0, 0, 0);
            }
            s[ct] = a;
        }

        // ---- online softmax (per q-row r; row lives in 16-lane group)
        #pragma unroll
        for (int r = 0; r < 4; ++r) {
            float rowmax = fmaxf(fmaxf(s[0][r], s[1][r]), fmaxf(s[2][r], s[3][r]));
            #pragma unroll
            for (int off = 1; off < 16; off <<= 1)
                rowmax = fmaxf(rowmax, __shfl_xor(rowmax, off));
            const float mnew = fmaxf(m[r], rowmax);
            const float sc   = __expf(m[r] - mnew);
            m[r] = mnew;
            float rs = 0.f;
            #pragma unroll
            for (int ct = 0; ct < 4; ++ct) {
                float p = __expf(s[ct][r] - mnew);
                s[ct][r] = p;
                rs += p;
            }
            #pragma unroll
            for (int off = 1; off < 16; off <<= 1)
                rs += __shfl_xor(rs, off);
            l[r] = l[r] * sc + rs;
            #pragma unroll
            for (int dt = 0; dt < 8; ++dt) acc[dt][r] *= sc;
        }

        // ---- P (C/D layout) -> LDS (XOR-swizzled) -> A-fragment layout
        _Float16* pbase = &P_lds[wave * 16 * PPAD];
        #pragma unroll
        for (int ct = 0; ct < 4; ++ct)
            #pragma unroll
            for (int r = 0; r < 4; ++r)
                pbase[(g * 4 + r) * PPAD + ((ct * 16 + lg) ^ (g << 3))] = (_Float16)s[ct][r];

        // ---- O += P * V  (V via ds_read_b64_tr_b16 from subtiled layout)
        #pragma unroll
        for (int kt = 0; kt < 2; ++kt) {
            f16x8 pf = *(const f16x8*)&pbase[lg * PPAD + ((kt * 32 + g * 8) ^ ((lg >> 2) << 3))];
            #pragma unroll
            for (int dp = 0; dp < 4; ++dp) {
                f16x4 a0, a1, b0, b1;
                asm volatile(
                    "ds_read_b64_tr_b16 %0, %4 offset:%5\n\t"
                    "ds_read_b64_tr_b16 %1, %4 offset:%6\n\t"
                    "ds_read_b64_tr_b16 %2, %4 offset:%7\n\t"
                    "ds_read_b64_tr_b16 %3, %4 offset:%8\n\t"
                    "s_waitcnt lgkmcnt(0)"
                    : "=&v"(a0), "=&v"(a1), "=&v"(b0), "=&v"(b1)
                    : "v"(trbase),
                      "i"(kt * 8192 + (dp * 2 + 0) * 128),
                      "i"(kt * 8192 + 1024 + (dp * 2 + 0) * 128),
                      "i"(kt * 8192 + (dp * 2 + 1) * 128),
                      "i"(kt * 8192 + 1024 + (dp * 2 + 1) * 128)
                    : "memory");
                __builtin_amdgcn_sched_barrier(0);
                f16x8 vf0 = __builtin_shufflevector(a0, a1, 0, 1, 2, 3, 4, 5, 6, 7);
                f16x8 vf1 = __builtin_shufflevector(b0, b1, 0, 1, 2, 3, 4, 5, 6, 7);
                acc[dp * 2 + 0] = __builtin_amdgcn_mfma_f32_16x16x32_f16(pf, vf0, acc[dp * 2 + 0], 0, 0, 0);
                acc[dp * 2 + 1] = __builtin_amdgcn_mfma_f32_16x16x32_f16(pf, vf1, acc[dp * 2 + 1], 0, 0, 0);
            }
        }
        __syncthreads();
    }

    // ---- epilogue: O / l
    float inv[4];
    #pragma unroll
    for (int r = 0; r < 4; ++r) inv[r] = 1.f / l[r];
    float* ob = Og + (size_t)(wave * 16) * DHEAD;
    #pragma unroll
    for (int dt = 0; dt < 8; ++dt)
        #pragma unroll
        for (int r = 0; r < 4; ++r)
            ob[(size_t)(g * 4 + r) * DHEAD + dt * 16 + lg] = acc[dt][r] * inv[r];
}

extern "C" void kernel_launch(void* const* d_in, const int* in_sizes, int n_in,
                              void* d_out, int out_size, void* d_ws, size_t ws_size,
                              hipStream_t stream) {
    const float* q = (const float*)d_in[0];
    const float* k = (const float*)d_in[1];
    const float* v = (const float*)d_in[2];
    float* out = (float*)d_out;
    const int BH = in_sizes[0] / (SEQ * DHEAD);   // 64
    dim3 grid(SEQ / QBLK, BH);
    attn_fwd_kernel<<<grid, dim3(256), 0, stream>>>(q, k, v, out);
}